// Round 5
// baseline (760.946 us; speedup 1.0000x reference)
//
#include <hip/hip_runtime.h>

// VolumeRotation via LDS tiling: B=8, C=16, S=64.
// Each block handles a 16x8x8 output tile for one batch. The rotated
// bounding region of the tile (provably <= 8000 floats incl. +3/axis slack)
// is staged into LDS per channel, then each point does 8 LDS reads + weights.
//
// History:
//  R0 (208 us): LDS tiling 16x8x8, fixed 16 staging iters, launch_bounds(512,4).
//  R1 (306 us): swizzle OK (FETCH 318->119 MB); break-guard rolled loops
//               -> scratch. Reverted.
//  R2 (634 us): no-LDS direct gather -> L1 line-touch bound. Refuted.
//  R3 (213 us): dynamic staging (3x less staging work) -> FLAT. Occupancy
//               stuck at 34% (launch_bounds 2nd arg empirically CAPS waves/EU).
//  R4 (221 us): 8^3 tile + dbuf + (512,8): occupancy 74% but FLAT - finer
//               tile costs ~1.5x line-touches (halo 3.6x, half-line stores).
//  R5: two-factor fix = R3 memory shape (16x8x8: full-line stores, long rows)
//      + R4 occupancy ((512,8) -> 4 blocks/CU) + odd LDS strides (ex|=1,
//      ey|=1) to derotate bank conflicts (1.5e7 conflict cycles in R3/R4).

#define S 64
#define SP (S * S * S)
#define CCH 16
#define BB 8

#define TW 16
#define TH 8
#define TD 8
#define NT 512           // threads per block
#define PPT 2            // points per thread (1024 points / 512 threads)
#define CAP 8192         // LDS floats capacity (worst-case region <= 8000
                         // with +3/axis slack; our +2 plus odd-pad +1 <= +3)
#define MAXIT 16         // CAP / NT max staging iterations

__global__ __launch_bounds__(NT, 8) void vol_rot_tiled(
    const float* __restrict__ vol,   // [B, C, S, S, S]
    const float* __restrict__ rot,   // [B, 3, 3]
    float* __restrict__ out)         // [B, C, S, S, S]
{
    __shared__ float smem[CAP + 2];

    const int tid = threadIdx.x;

    // ---- XCD-contiguous swizzle: XCD k (= blockIdx%8) gets blocks
    //      [k*256, (k+1)*256) of the logical grid = exactly batch k. ----
    const int wg = (blockIdx.x & 7) * (BB * 256 / 8) + (blockIdx.x >> 3);
    const int t  = wg & 255;
    const int b  = wg >> 8;
    const int w0 = (t & 3) * TW;
    const int h0 = ((t >> 2) & 7) * TH;
    const int d0 = (t >> 5) * TD;

    const float* R = rot + b * 9;    // wave-uniform -> scalar loads
    const float R00 = R[0], R01 = R[1], R02 = R[2];
    const float R10 = R[3], R11 = R[4], R12 = R[5];
    const float R20 = R[6], R21 = R[7], R22 = R[8];

    const float st = 2.0f / 63.0f;

    // ---- bounding box of the tile's sample positions (affine -> corners) ----
    float xmn = 1e30f, xmx = -1e30f;
    float ymn = 1e30f, ymx = -1e30f;
    float zmn = 1e30f, zmx = -1e30f;
#pragma unroll
    for (int k = 0; k < 8; ++k) {
        const float xb = -1.0f + (float)(w0 + ((k & 1) ? (TW - 1) : 0)) * st;
        const float yb = -1.0f + (float)(h0 + ((k & 2) ? (TH - 1) : 0)) * st;
        const float zb = -1.0f + (float)(d0 + ((k & 4) ? (TD - 1) : 0)) * st;
        const float gx = R00 * xb + R10 * yb + R20 * zb;
        const float gy = R01 * xb + R11 * yb + R21 * zb;
        const float gz = R02 * xb + R12 * yb + R22 * zb;
        const float vx = (gx + 1.0f) * 32.0f - 0.5f;
        const float vy = (gy + 1.0f) * 32.0f - 0.5f;
        const float vz = (gz + 1.0f) * 32.0f - 0.5f;
        xmn = fminf(xmn, vx); xmx = fmaxf(xmx, vx);
        ymn = fminf(ymn, vy); ymx = fmaxf(ymx, vy);
        zmn = fminf(zmn, vz); zmx = fmaxf(zmx, vz);
    }
    const int rx0 = (int)floorf(xmn);
    const int ry0 = (int)floorf(ymn);
    const int rz0 = (int)floorf(zmn);
    int ex = (int)floorf(xmx) + 2 - rx0;   // region extents (>=2, <=21)
    int ey = (int)floorf(ymx) + 2 - ry0;
    int ez = (int)floorf(zmx) + 2 - rz0;
    ex |= 1;                               // odd strides: y/z row steps rotate
    ey |= 1;                               // across the 32 LDS banks
    if (ex * ey * ez > CAP) ez = CAP / (ex * ey);   // safety (unreachable)

    const int plane = ex * ey;
    const int rsz   = plane * ez;              // actual region size (<= CAP)
    const int nit   = (rsz + NT - 1) >> 9;     // staging iterations (1..16)
    const float invp = 1.0f / (float)plane;
    const float inve = 1.0f / (float)ex;

    // ---- staging address precompute (shared across all 16 channels) ----
    // Guard-per-iteration with LITERAL indices: arrays stay in registers.
    int voff[MAXIT];        // byte offset into one channel's volume (clamped)
    unsigned mask = 0;      // bit i: coordinate inside volume
#define STAGE_ADDR(i)                                                         \
    if (nit > (i)) {                                                          \
        const int r  = tid + (i) * NT;                                        \
        const int rz = (int)(((float)r + 0.5f) * invp);                       \
        const int rm = r - rz * plane;                                        \
        const int ry = (int)(((float)rm + 0.5f) * inve);                      \
        const int rx = rm - ry * ex;                                          \
        const int gx = rx0 + rx, gy = ry0 + ry, gz = rz0 + rz;                \
        const bool valid = ((unsigned)gx < 64u) & ((unsigned)gy < 64u)        \
                         & ((unsigned)gz < 64u);                              \
        const int gxc = min(max(gx, 0), 63);                                  \
        const int gyc = min(max(gy, 0), 63);                                  \
        const int gzc = min(max(gz, 0), 63);                                  \
        voff[i] = (((((gzc << 6) + gyc) << 6) + gxc) << 2);                   \
        mask |= ((unsigned)valid) << (i);                                     \
    }
    STAGE_ADDR(0)  STAGE_ADDR(1)  STAGE_ADDR(2)  STAGE_ADDR(3)
    STAGE_ADDR(4)  STAGE_ADDR(5)  STAGE_ADDR(6)  STAGE_ADDR(7)
    STAGE_ADDR(8)  STAGE_ADDR(9)  STAGE_ADDR(10) STAGE_ADDR(11)
    STAGE_ADDR(12) STAGE_ADDR(13) STAGE_ADDR(14) STAGE_ADDR(15)
#undef STAGE_ADDR

    // ---- per-point state (shared across channels) ----
    int   obase[PPT];       // LDS byte offset of (z0,y0,x0) corner
    int   ospat[PPT];       // output spatial index
    float wgt[PPT][8];      // trilinear weights, k = dz*4+dy*2+dx
#pragma unroll
    for (int p = 0; p < PPT; ++p) {
        const int idx = tid + p * NT;
        const int pw = idx & 15, ph = (idx >> 4) & 7, pd = idx >> 7;
        const float xb = -1.0f + (float)(w0 + pw) * st;
        const float yb = -1.0f + (float)(h0 + ph) * st;
        const float zb = -1.0f + (float)(d0 + pd) * st;
        const float gx = R00 * xb + R10 * yb + R20 * zb;
        const float gy = R01 * xb + R11 * yb + R21 * zb;
        const float gz = R02 * xb + R12 * yb + R22 * zb;
        const float vx = (gx + 1.0f) * 32.0f - 0.5f;
        const float vy = (gy + 1.0f) * 32.0f - 0.5f;
        const float vz = (gz + 1.0f) * 32.0f - 0.5f;
        const float fx = floorf(vx), fy = floorf(vy), fz = floorf(vz);
        const float tx = vx - fx, ty = vy - fy, tz = vz - fz;
        int lx = (int)fx - rx0, ly = (int)fy - ry0, lz = (int)fz - rz0;
        lx = min(max(lx, 0), ex - 2);   // clamp only engages when weight==0
        ly = min(max(ly, 0), ey - 2);   // or ~1e-5 (fp rounding at edges)
        lz = min(max(lz, 0), ez - 2);
        obase[p] = ((lz * ey + ly) * ex + lx) * 4;
        ospat[p] = ((d0 + pd) * 64 + (h0 + ph)) * 64 + (w0 + pw);
        const float ux = 1.0f - tx, uy = 1.0f - ty, uz = 1.0f - tz;
        wgt[p][0] = uz * uy * ux; wgt[p][1] = uz * uy * tx;
        wgt[p][2] = uz * ty * ux; wgt[p][3] = uz * ty * tx;
        wgt[p][4] = tz * uy * ux; wgt[p][5] = tz * uy * tx;
        wgt[p][6] = tz * ty * ux; wgt[p][7] = tz * ty * tx;
    }

    // ---- channel loop: stage region -> LDS, then sample ----
    const char* smemb = (const char*)smem;
    const int dy4 = ex * 4;
    const int dz4 = plane * 4;
    const float* volb = vol + (size_t)b * CCH * SP;
    float*       outb = out + (size_t)b * CCH * SP;

    float vals[MAXIT];
#define PREFETCH(i, vc)                                                       \
    if (nit > (i)) vals[i] = *(const float*)((vc) + voff[i]);
#define LDS_WRITE(i)                                                          \
    if (nit > (i))                                                            \
        smem[tid + (i) * NT] = ((mask >> (i)) & 1u) ? vals[i] : 0.0f;

    // prefetch channel 0 (only the needed iterations)
    {
        const char* vc = (const char*)volb;
        PREFETCH(0, vc)  PREFETCH(1, vc)  PREFETCH(2, vc)  PREFETCH(3, vc)
        PREFETCH(4, vc)  PREFETCH(5, vc)  PREFETCH(6, vc)  PREFETCH(7, vc)
        PREFETCH(8, vc)  PREFETCH(9, vc)  PREFETCH(10, vc) PREFETCH(11, vc)
        PREFETCH(12, vc) PREFETCH(13, vc) PREFETCH(14, vc) PREFETCH(15, vc)
    }

    for (int c = 0; c < CCH; ++c) {
        __syncthreads();    // previous channel's sampling done
        LDS_WRITE(0)  LDS_WRITE(1)  LDS_WRITE(2)  LDS_WRITE(3)
        LDS_WRITE(4)  LDS_WRITE(5)  LDS_WRITE(6)  LDS_WRITE(7)
        LDS_WRITE(8)  LDS_WRITE(9)  LDS_WRITE(10) LDS_WRITE(11)
        LDS_WRITE(12) LDS_WRITE(13) LDS_WRITE(14) LDS_WRITE(15)
        __syncthreads();    // region visible

        // prefetch next channel's region (overlaps with sampling below)
        if (c + 1 < CCH) {
            const char* vc = (const char*)(volb + (c + 1) * SP);
            PREFETCH(0, vc)  PREFETCH(1, vc)  PREFETCH(2, vc)  PREFETCH(3, vc)
            PREFETCH(4, vc)  PREFETCH(5, vc)  PREFETCH(6, vc)  PREFETCH(7, vc)
            PREFETCH(8, vc)  PREFETCH(9, vc)  PREFETCH(10, vc) PREFETCH(11, vc)
            PREFETCH(12, vc) PREFETCH(13, vc) PREFETCH(14, vc) PREFETCH(15, vc)
        }

#pragma unroll
        for (int p = 0; p < PPT; ++p) {
            const char* pb = smemb + obase[p];
            const float v000 = *(const float*)(pb);
            const float v001 = *(const float*)(pb + 4);
            const float v010 = *(const float*)(pb + dy4);
            const float v011 = *(const float*)(pb + dy4 + 4);
            const float v100 = *(const float*)(pb + dz4);
            const float v101 = *(const float*)(pb + dz4 + 4);
            const float v110 = *(const float*)(pb + dz4 + dy4);
            const float v111 = *(const float*)(pb + dz4 + dy4 + 4);
            const float acc = wgt[p][0] * v000 + wgt[p][1] * v001
                            + wgt[p][2] * v010 + wgt[p][3] * v011
                            + wgt[p][4] * v100 + wgt[p][5] * v101
                            + wgt[p][6] * v110 + wgt[p][7] * v111;
            outb[c * SP + ospat[p]] = acc;
        }
    }
#undef PREFETCH
#undef LDS_WRITE
}

extern "C" void kernel_launch(void* const* d_in, const int* in_sizes, int n_in,
                              void* d_out, int out_size, void* d_ws, size_t ws_size,
                              hipStream_t stream) {
    const float* vol = (const float*)d_in[0];
    const float* rot = (const float*)d_in[1];
    float* out = (float*)d_out;

    // 8 batches x (4 x 8 x 8) tiles = 2048 blocks
    vol_rot_tiled<<<dim3(BB * 256), dim3(NT), 0, stream>>>(vol, rot, out);
}

// Round 7
// 365.880 us; speedup vs baseline: 2.0798x; 2.0798x over previous
//
#include <hip/hip_runtime.h>

// VolumeRotation via LDS tiling + global_load_lds staging: B=8, C=16, S=64.
// Each block: one 16x8x8 output tile for one batch. Rotated bounding region
// (<= 8000 floats) staged direct-to-LDS per channel; each point does 8 LDS
// reads + factored trilinear lerp.
//
// History:
//  R0 (208 us): LDS tiling 16x8x8, reg round-trip staging, bounds(512,4).
//  R1 (306 us): break-guard rolled loops -> scratch. Reverted.
//  R2 (634 us): no-LDS gather -> L1 line-touch bound. Refuted.
//  R3 (213 us): dynamic staging -> FLAT; occupancy capped ~34% by bounds arg.
//  R4 (221 us): 8^3+dbuf+(512,8): occ 74%, VGPR forced 32, worse halo. Flat.
//  R5 (627 us): 16x8x8+(512,8): ~60 live regs vs 32 VGPR -> massive spill.
//  R6 (FAIL): exec-masked global_load_lds -> LDS base comes from FIRST
//             ACTIVE lane; masked-off prefix lanes shift the whole wave's
//             destination. Lesson: gllds needs full-exec, uniform control.
//  R7: same structure, correct OOB handling: all lanes always execute
//      gllds; invalid lanes' GLOBAL source (per-lane, legal) is redirected
//      to a zero-initialized __device__ array -> real 0.0f lands in their
//      LDS slot each channel. No divergence around gllds, no pre-zero.

#define S 64
#define SP (S * S * S)
#define SPB (SP * 4)
#define CCH 16
#define BB 8

#define TW 16
#define TH 8
#define TD 8
#define NT 512           // threads per block
#define PPT 2            // points per thread (1024 points / 512 threads)
#define CAP 8192         // LDS floats capacity (worst-case region <= 8000)
#define MAXIT 16         // CAP / NT max staging iterations

typedef const __attribute__((address_space(1))) void* gas1_t;
typedef __attribute__((address_space(3))) void* las3_t;

__device__ float g_zero[64];   // zero-initialized at module load; never written

__global__ __launch_bounds__(NT, 6) void vol_rot_glds(
    const float* __restrict__ vol,   // [B, C, S, S, S]
    const float* __restrict__ rot,   // [B, 3, 3]
    float* __restrict__ out)         // [B, C, S, S, S]
{
    __shared__ float smem[CAP + 2];

    const int tid = threadIdx.x;

    // ---- XCD-contiguous swizzle: XCD k (= blockIdx%8) gets blocks
    //      [k*256,(k+1)*256) = exactly batch k. ----
    const int wg = (blockIdx.x & 7) * 256 + (blockIdx.x >> 3);
    const int t  = wg & 255;
    const int b  = wg >> 8;
    const int w0 = (t & 3) * TW;
    const int h0 = ((t >> 2) & 7) * TH;
    const int d0 = (t >> 5) * TD;

    const float* R = rot + b * 9;    // wave-uniform -> scalar loads
    const float R00 = R[0], R01 = R[1], R02 = R[2];
    const float R10 = R[3], R11 = R[4], R12 = R[5];
    const float R20 = R[6], R21 = R[7], R22 = R[8];

    const float st = 2.0f / 63.0f;

    // ---- bounding box of the tile's sample positions ----
    float xmn = 1e30f, xmx = -1e30f;
    float ymn = 1e30f, ymx = -1e30f;
    float zmn = 1e30f, zmx = -1e30f;
#pragma unroll
    for (int k = 0; k < 8; ++k) {
        const float xb = -1.0f + (float)(w0 + ((k & 1) ? (TW - 1) : 0)) * st;
        const float yb = -1.0f + (float)(h0 + ((k & 2) ? (TH - 1) : 0)) * st;
        const float zb = -1.0f + (float)(d0 + ((k & 4) ? (TD - 1) : 0)) * st;
        const float gx = R00 * xb + R10 * yb + R20 * zb;
        const float gy = R01 * xb + R11 * yb + R21 * zb;
        const float gz = R02 * xb + R12 * yb + R22 * zb;
        const float vx = (gx + 1.0f) * 32.0f - 0.5f;
        const float vy = (gy + 1.0f) * 32.0f - 0.5f;
        const float vz = (gz + 1.0f) * 32.0f - 0.5f;
        xmn = fminf(xmn, vx); xmx = fmaxf(xmx, vx);
        ymn = fminf(ymn, vy); ymx = fmaxf(ymx, vy);
        zmn = fminf(zmn, vz); zmx = fmaxf(zmx, vz);
    }
    const int rx0 = (int)floorf(xmn);
    const int ry0 = (int)floorf(ymn);
    const int rz0 = (int)floorf(zmn);
    const int ex = (int)floorf(xmx) + 2 - rx0;   // region extents (>=2, <=21)
    const int ey = (int)floorf(ymx) + 2 - ry0;
    int ez = (int)floorf(zmx) + 2 - rz0;
    if (ex * ey * ez > CAP) ez = CAP / (ex * ey);   // safety (unreachable)

    const int plane = ex * ey;
    const int rsz   = plane * ez;              // actual region size (<= CAP)
    int nit = (rsz + NT - 1) >> 9;             // staging iterations (1..16)
    nit = __builtin_amdgcn_readfirstlane(nit); // scalar -> uniform branches
    const float invp = 1.0f / (float)plane;
    const float inve = 1.0f / (float)ex;

    // ---- staging address precompute (shared across all 16 channels) ----
    int voff[MAXIT];        // byte offset into one channel's volume (clamped)
    unsigned mask = 0;      // bit i: coordinate inside volume
#define STAGE_ADDR(i)                                                         \
    if (nit > (i)) {                                                          \
        const int r  = tid + (i) * NT;                                        \
        const int rz = (int)(((float)r + 0.5f) * invp);                       \
        const int rm = r - rz * plane;                                        \
        const int ry = (int)(((float)rm + 0.5f) * inve);                      \
        const int rx = rm - ry * ex;                                          \
        const int gx = rx0 + rx, gy = ry0 + ry, gz = rz0 + rz;                \
        const bool valid = ((unsigned)gx < 64u) & ((unsigned)gy < 64u)        \
                         & ((unsigned)gz < 64u);                              \
        const int gxc = min(max(gx, 0), 63);                                  \
        const int gyc = min(max(gy, 0), 63);                                  \
        const int gzc = min(max(gz, 0), 63);                                  \
        voff[i] = (((((gzc << 6) + gyc) << 6) + gxc) << 2);                   \
        mask |= ((unsigned)valid) << (i);                                     \
    }
    STAGE_ADDR(0)  STAGE_ADDR(1)  STAGE_ADDR(2)  STAGE_ADDR(3)
    STAGE_ADDR(4)  STAGE_ADDR(5)  STAGE_ADDR(6)  STAGE_ADDR(7)
    STAGE_ADDR(8)  STAGE_ADDR(9)  STAGE_ADDR(10) STAGE_ADDR(11)
    STAGE_ADDR(12) STAGE_ADDR(13) STAGE_ADDR(14) STAGE_ADDR(15)
#undef STAGE_ADDR

    // ---- per-point state: fractions + LDS corner offset (small!) ----
    float tfx[PPT], tfy[PPT], tfz[PPT];
    int   obase[PPT];
    int   ospat0;           // p=1 output offset is ospat0 + 4*64*64
#pragma unroll
    for (int p = 0; p < PPT; ++p) {
        const int idx = tid + p * NT;
        const int pw = idx & 15, ph = (idx >> 4) & 7, pd = idx >> 7;
        const float xb = -1.0f + (float)(w0 + pw) * st;
        const float yb = -1.0f + (float)(h0 + ph) * st;
        const float zb = -1.0f + (float)(d0 + pd) * st;
        const float gx = R00 * xb + R10 * yb + R20 * zb;
        const float gy = R01 * xb + R11 * yb + R21 * zb;
        const float gz = R02 * xb + R12 * yb + R22 * zb;
        const float vx = (gx + 1.0f) * 32.0f - 0.5f;
        const float vy = (gy + 1.0f) * 32.0f - 0.5f;
        const float vz = (gz + 1.0f) * 32.0f - 0.5f;
        const float fx = floorf(vx), fy = floorf(vy), fz = floorf(vz);
        tfx[p] = vx - fx; tfy[p] = vy - fy; tfz[p] = vz - fz;
        int lx = (int)fx - rx0, ly = (int)fy - ry0, lz = (int)fz - rz0;
        lx = min(max(lx, 0), ex - 2);   // clamp only engages when weight==0
        ly = min(max(ly, 0), ey - 2);   // or ~1e-5 (fp rounding at edges)
        lz = min(max(lz, 0), ez - 2);
        obase[p] = ((lz * ey + ly) * ex + lx) * 4;
        if (p == 0)
            ospat0 = ((d0 + pd) * 64 + (h0 + ph)) * 64 + (w0 + pw);
    }

    const char* smemb = (const char*)smem;
    const int dy4 = ex * 4;
    const int dz4 = plane * 4;
    const char*  vcb  = (const char*)vol + (size_t)b * CCH * SPB;
    const char*  zptr = (const char*)g_zero;
    float*       outc = out + (size_t)b * CCH * SP;

    // ---- channel loop: full-exec gllds (invalid lanes source g_zero),
    //      barrier (drains vmcnt), sample, barrier. ----
#define GLLDS(i)                                                              \
    if (nit > (i)) {                                                          \
        const char* src = ((mask >> (i)) & 1u) ? (vcb + voff[i]) : zptr;      \
        __builtin_amdgcn_global_load_lds(                                     \
            (gas1_t)(const void*)src,                                         \
            (las3_t)(void*)&smem[tid + (i) * NT], 4, 0, 0);                   \
    }

    for (int c = 0; c < CCH; ++c) {
        GLLDS(0)  GLLDS(1)  GLLDS(2)  GLLDS(3)
        GLLDS(4)  GLLDS(5)  GLLDS(6)  GLLDS(7)
        GLLDS(8)  GLLDS(9)  GLLDS(10) GLLDS(11)
        GLLDS(12) GLLDS(13) GLLDS(14) GLLDS(15)
        __syncthreads();    // vmcnt drained by compiler -> region visible

#pragma unroll
        for (int p = 0; p < PPT; ++p) {
            const char* pb = smemb + obase[p];
            const float v000 = *(const float*)(pb);
            const float v001 = *(const float*)(pb + 4);
            const float v010 = *(const float*)(pb + dy4);
            const float v011 = *(const float*)(pb + dy4 + 4);
            const float v100 = *(const float*)(pb + dz4);
            const float v101 = *(const float*)(pb + dz4 + 4);
            const float v110 = *(const float*)(pb + dz4 + dy4);
            const float v111 = *(const float*)(pb + dz4 + dy4 + 4);
            const float tx = tfx[p], ty = tfy[p], tz = tfz[p];
            const float a00 = v000 + tx * (v001 - v000);
            const float a01 = v010 + tx * (v011 - v010);
            const float a10 = v100 + tx * (v101 - v100);
            const float a11 = v110 + tx * (v111 - v110);
            const float b0  = a00 + ty * (a01 - a00);
            const float b1  = a10 + ty * (a11 - a10);
            const float acc = b0 + tz * (b1 - b0);
            outc[ospat0 + p * (4 * 64 * 64)] = acc;
        }
        __syncthreads();    // sampling done before next channel overwrites
        vcb  += SPB;
        outc += SP;
    }
#undef GLLDS
}

extern "C" void kernel_launch(void* const* d_in, const int* in_sizes, int n_in,
                              void* d_out, int out_size, void* d_ws, size_t ws_size,
                              hipStream_t stream) {
    const float* vol = (const float*)d_in[0];
    const float* rot = (const float*)d_in[1];
    float* out = (float*)d_out;

    // 8 batches x (4 x 8 x 8) tiles = 2048 blocks
    vol_rot_glds<<<dim3(BB * 256), dim3(NT), 0, stream>>>(vol, rot, out);
}